// Round 11
// baseline (10238.942 us; speedup 1.0000x reference)
//
#include <hip/hip_runtime.h>
#include <math.h>

#define T_SEQ 365
#define HDIM 256
#define NHEADS 8
#define HD 32
#define BATCH 256
#define DDIM 16
#define FFDIM 1024
#define NST 10000
#define KNB 5
#define SDIM 64

typedef __bf16 bf16x8 __attribute__((ext_vector_type(8)));
typedef float  f32x16 __attribute__((ext_vector_type(16)));
typedef unsigned short u16x8 __attribute__((ext_vector_type(8)));

__device__ __forceinline__ ushort f2b_hi(float v) {
    unsigned u = __float_as_uint(v);
    unsigned r = u + 0x7fffu + ((u >> 16) & 1u);
    return (ushort)(r >> 16);
}
__device__ __forceinline__ float b2f(ushort h) {
    return __uint_as_float(((unsigned)h) << 16);
}
__device__ __forceinline__ ushort f2b_lo(float v, ushort hi) {
    return f2b_hi(v - b2f(hi));
}

__device__ __forceinline__ float gelu_f(float x) {
    return 0.5f * x * (1.f + erff(x * 0.70710678118654752f));
}

// FT (fragment-tiled) layout for a [R][C] bf16 matrix, C%8==0:
// offset(r,c) = ((r>>5)*(C>>3) + (c>>3))*256 + (r&31)*8 + (c&7)
// Per-(b,h) attention buffers: Q,K = FT over [384 tok][32 d] (12288 ushorts);
// V^T = FT over [32 d][384 tok]: offset(d,tok) = (tok>>3)*256 + d*8 + (tok&7).

// block-wide (256 threads = 4 waves) sum; sred must be float[4] shared
__device__ __forceinline__ float block_sum256(float v, float* sred) {
    #pragma unroll
    for (int off = 32; off; off >>= 1) v += __shfl_xor(v, off);
    int wave = threadIdx.x >> 6;
    if ((threadIdx.x & 63) == 0) sred[wave] = v;
    __syncthreads();
    float s = sred[0] + sred[1] + sred[2] + sred[3];
    __syncthreads();
    return s;
}

// ---------------- top-K neighbor search ----------------
__global__ __launch_bounds__(256) void topk_kernel(
    const float* __restrict__ lat, const float* __restrict__ lon,
    const float* __restrict__ coords, int* __restrict__ nbr)
{
    __shared__ float hav[NST];
    __shared__ float rv[256];
    __shared__ int   ri[256];
    const float DEG = 0.017453292519943295f;
    int b = blockIdx.x, t = threadIdx.x;
    float lat_o = (lat[b] + 1.f) * 0.5f * 25.f + 24.f;
    float lon_o = (lon[b] + 1.f) * 0.5f * 58.5f - 125.f;
    float qlat = lat_o * DEG, qlon = lon_o * DEG;
    float cq = cosf(qlat);
    for (int i = t; i < NST; i += 256) {
        float slat = coords[2*i], slon = coords[2*i+1];
        float dlat = qlat - slat, dlon = qlon - slon;
        float s1 = sinf(dlat * 0.5f), s2 = sinf(dlon * 0.5f);
        hav[i] = s1*s1 + cq * cosf(slat) * s2*s2;
    }
    __syncthreads();
    for (int sel = 0; sel < KNB + 1; ++sel) {
        float bv = 1e30f; int bi = 0x7fffffff;
        for (int i = t; i < NST; i += 256) {
            float v = hav[i];
            if (v < bv || (v == bv && i < bi)) { bv = v; bi = i; }
        }
        rv[t] = bv; ri[t] = bi;
        __syncthreads();
        for (int s = 128; s > 0; s >>= 1) {
            if (t < s) {
                float ov = rv[t+s]; int oi = ri[t+s];
                if (ov < rv[t] || (ov == rv[t] && oi < ri[t])) { rv[t] = ov; ri[t] = oi; }
            }
            __syncthreads();
        }
        if (t == 0) {
            if (sel > 0) nbr[b*KNB + sel - 1] = ri[0];
            hav[ri[0]] = 1e30f;   // mask winner
        }
        __syncthreads();
    }
}

// ---------------- static-feature branch ----------------
__global__ __launch_bounds__(256) void sfeat_kernel(
    const float* __restrict__ stat, const float* __restrict__ all_st,
    const int* __restrict__ nbr, const float* __restrict__ W,
    const float* __restrict__ bias, const float* __restrict__ g,
    const float* __restrict__ be, float* __restrict__ sfeat)
{
    __shared__ float comb[(KNB+1)*SDIM]; // 384
    __shared__ float sred[4];
    int b = blockIdx.x, t = threadIdx.x;
    for (int i = t; i < (KNB+1)*SDIM; i += 256) {
        if (i < SDIM) comb[i] = stat[b*SDIM + i];
        else {
            int n = (i - SDIM) >> 6, d = (i - SDIM) & 63;
            comb[i] = all_st[(size_t)nbr[b*KNB + n] * SDIM + d];
        }
    }
    __syncthreads();
    float acc = bias[t];
    for (int j = 0; j < (KNB+1)*SDIM; ++j)
        acc = fmaf(comb[j], W[j*HDIM + t], acc);
    float mu  = block_sum256(acc, sred) * (1.f/256.f);
    float d   = acc - mu;
    float var = block_sum256(d*d, sred) * (1.f/256.f);
    float y = g[t] * d * rsqrtf(var + 1e-5f) + be[t];
    sfeat[(size_t)b*HDIM + t] = gelu_f(y);
}

// ------ dynamic embedding (per-chunk): 4 rows/block, wave per row ------
__global__ __launch_bounds__(256) void dyn_kernel(
    const float* __restrict__ dynv, const float* __restrict__ W,
    const float* __restrict__ bias, const float* __restrict__ g,
    const float* __restrict__ be, const float* __restrict__ sfeatc,
    ushort* __restrict__ xhi, ushort* __restrict__ xlo)
{
    __shared__ float w[DDIM*HDIM];   // 16 KB
    __shared__ float dr[4][DDIM];
    int wave = threadIdx.x >> 6, lane = threadIdx.x & 63;
    int row0 = blockIdx.x * 4;
    for (int i = threadIdx.x; i < DDIM*HDIM; i += 256) w[i] = W[i];
    if (lane < DDIM)
        dr[wave][lane] = dynv[(size_t)(row0 + wave)*DDIM + lane];
    __syncthreads();
    int row = row0 + wave;
    int b = row / T_SEQ;     // chunk-local batch index
    int c0 = lane * 4;
    float v0 = bias[c0], v1 = bias[c0+1], v2 = bias[c0+2], v3 = bias[c0+3];
    #pragma unroll
    for (int k = 0; k < DDIM; ++k) {
        float dk = dr[wave][k];
        float4 wv = *reinterpret_cast<const float4*>(&w[k*HDIM + c0]);
        v0 = fmaf(dk, wv.x, v0); v1 = fmaf(dk, wv.y, v1);
        v2 = fmaf(dk, wv.z, v2); v3 = fmaf(dk, wv.w, v3);
    }
    float s = v0 + v1 + v2 + v3;
    #pragma unroll
    for (int off = 32; off; off >>= 1) s += __shfl_xor(s, off);
    float mu = s * (1.f/256.f);
    float d0 = v0-mu, d1 = v1-mu, d2 = v2-mu, d3 = v3-mu;
    float s2 = d0*d0 + d1*d1 + d2*d2 + d3*d3;
    #pragma unroll
    for (int off = 32; off; off >>= 1) s2 += __shfl_xor(s2, off);
    float rs = rsqrtf(s2 * (1.f/256.f) + 1e-5f);
    float4 gg = *reinterpret_cast<const float4*>(&g[c0]);
    float4 bb = *reinterpret_cast<const float4*>(&be[c0]);
    float4 sf = *reinterpret_cast<const float4*>(&sfeatc[(size_t)b*HDIM + c0]);
    float o0 = gelu_f(gg.x*d0*rs + bb.x) + sf.x;
    float o1 = gelu_f(gg.y*d1*rs + bb.y) + sf.y;
    float o2 = gelu_f(gg.z*d2*rs + bb.z) + sf.z;
    float o3 = gelu_f(gg.w*d3*rs + bb.w) + sf.w;
    size_t o = ((size_t)(row >> 5) * 32 + (c0 >> 3)) * 256 + ((row & 31) << 3) + (c0 & 7);
    ushort4 hv, lv;
    hv.x = f2b_hi(o0); lv.x = f2b_lo(o0, hv.x);
    hv.y = f2b_hi(o1); lv.y = f2b_lo(o1, hv.y);
    hv.z = f2b_hi(o2); lv.z = f2b_lo(o2, hv.z);
    hv.w = f2b_hi(o3); lv.w = f2b_lo(o3, hv.w);
    *reinterpret_cast<ushort4*>(&xhi[o]) = hv;
    *reinterpret_cast<ushort4*>(&xlo[o]) = lv;
}

// --- weight transpose + split: W[L][K][N] -> FT([N][K]) hi/lo per layer ---
__global__ __launch_bounds__(256) void tsplit_kernel(
    const float* __restrict__ W, ushort* __restrict__ hi, ushort* __restrict__ lo,
    int K, int N)
{
    __shared__ float tile[32][33];
    size_t l = blockIdx.z;
    const float* Wl = W + l*(size_t)K*N;
    ushort* hil = hi + l*(size_t)K*N;
    ushort* lol = lo + l*(size_t)K*N;
    int n0 = blockIdx.x*32, k0 = blockIdx.y*32;
    int tx = threadIdx.x & 31, ty = threadIdx.x >> 5;
    int KB = K >> 3;
    for (int i = ty; i < 32; i += 8) tile[i][tx] = Wl[(size_t)(k0+i)*N + n0 + tx];
    __syncthreads();
    for (int i = ty; i < 32; i += 8) {
        float v = tile[tx][i];              // (k=k0+tx, n=n0+i)
        ushort h = f2b_hi(v);
        size_t o = ((size_t)(n0 >> 5) * KB + (k0 >> 3) + (tx >> 3)) * 256
                 + ((size_t)i << 3) + (tx & 7);
        hil[o] = h;
        lol[o] = f2b_lo(v, h);
    }
}

// ------- split-bf16 MFMA GEMM (qkv): FT operands, Q/K/V scatter out -------
// XCD-chunked block swizzle (bijective, any nwg) for A-panel L2 locality.
__global__ __launch_bounds__(256) void gemm_qkv(
    const ushort* __restrict__ Ahi, const ushort* __restrict__ Alo,
    const ushort* __restrict__ Bhi, const ushort* __restrict__ Blo,
    const float* __restrict__ bias,
    ushort* __restrict__ Wq_h, ushort* __restrict__ Wq_l,
    ushort* __restrict__ Wk_h, ushort* __restrict__ Wk_l,
    ushort* __restrict__ Wv_h, ushort* __restrict__ Wv_l,
    int M, int N, int K)
{
    const int t = threadIdx.x;
    const int lane = t & 63, wave = t >> 6;
    const int wr = wave >> 1, wc = wave & 1;
    const int lr = lane & 31, kg = lane >> 5;
    // bijective XCD swizzle (m204): consecutive work ids -> same XCD chunk
    int nwg = gridDim.x * gridDim.y;
    int orig = blockIdx.y * gridDim.x + blockIdx.x;
    int qq = nwg >> 3, rr = nwg & 7, xcd = orig & 7, idx = orig >> 3;
    int wgid = (xcd < rr ? xcd*(qq+1) : rr*(qq+1) + (xcd-rr)*qq) + idx;
    const int bx = wgid % gridDim.x;
    const int by = wgid / gridDim.x;
    const int row_b = by * 128 + wr * 64;
    const int col_b = bx * 128 + wc * 64;
    const int KB = K >> 3;

    const ushort *pAh[2], *pAl[2], *pBh[2], *pBl[2];
    #pragma unroll
    for (int mi = 0; mi < 2; ++mi) {
        int rb = row_b + mi*32; if (rb > M - 32) rb = M - 32;   // loads clamped
        size_t base = ((size_t)(rb >> 5) * KB + kg) * 256 + lr * 8;
        pAh[mi] = Ahi + base; pAl[mi] = Alo + base;
    }
    #pragma unroll
    for (int nj = 0; nj < 2; ++nj) {
        size_t base = ((size_t)((col_b + nj*32) >> 5) * KB + kg) * 256 + lr * 8;
        pBh[nj] = Bhi + base; pBl[nj] = Blo + base;
    }

    f32x16 acc[2][2];
    #pragma unroll
    for (int i = 0; i < 2; ++i)
        #pragma unroll
        for (int j = 0; j < 2; ++j)
            #pragma unroll
            for (int r = 0; r < 16; ++r) acc[i][j][r] = 0.f;

    bf16x8 a0h[2], a0l[2], b0h[2], b0l[2];
    bf16x8 a1h[2], a1l[2], b1h[2], b1l[2];

#define LOADF(AH, AL, BH, BL, OFF) do {                                        \
    _Pragma("unroll") for (int mi = 0; mi < 2; ++mi) {                         \
        AH[mi] = *reinterpret_cast<const bf16x8*>(pAh[mi] + (OFF));            \
        AL[mi] = *reinterpret_cast<const bf16x8*>(pAl[mi] + (OFF)); }          \
    _Pragma("unroll") for (int nj = 0; nj < 2; ++nj) {                         \
        BH[nj] = *reinterpret_cast<const bf16x8*>(pBh[nj] + (OFF));            \
        BL[nj] = *reinterpret_cast<const bf16x8*>(pBl[nj] + (OFF)); } } while(0)

#define MFMAF(AH, AL, BH, BL) do {                                             \
    _Pragma("unroll") for (int mi = 0; mi < 2; ++mi)                           \
    _Pragma("unroll") for (int nj = 0; nj < 2; ++nj) {                         \
        acc[mi][nj] = __builtin_amdgcn_mfma_f32_32x32x16_bf16(                 \
            AH[mi], BH[nj], acc[mi][nj], 0, 0, 0);                             \
        acc[mi][nj] = __builtin_amdgcn_mfma_f32_32x32x16_bf16(                 \
            AH[mi], BL[nj], acc[mi][nj], 0, 0, 0);                             \
        acc[mi][nj] = __builtin_amdgcn_mfma_f32_32x32x16_bf16(                 \
            AL[mi], BH[nj], acc[mi][nj], 0, 0, 0); } } while(0)

    LOADF(a0h, a0l, b0h, b0l, 0);
    for (int k0 = 0; k0 < K; k0 += 32) {
        size_t o1 = (size_t)((k0 + 16) >> 3) * 256;
        LOADF(a1h, a1l, b1h, b1l, o1);
        MFMAF(a0h, a0l, b0h, b0l);
        size_t o2 = (k0 + 32 < K) ? (size_t)((k0 + 32) >> 3) * 256 : 0;
        LOADF(a0h, a0l, b0h, b0l, o2);       // last iteration: harmless reload
        MFMAF(a1h, a1l, b1h, b1l);
    }
#undef LOADF
#undef MFMAF

    // epilogue: C/D map: col = lane&31, row31 = (r&3)+8*(r>>2)+4*kg
    #pragma unroll
    for (int mi = 0; mi < 2; ++mi) {
        int rb2 = row_b + mi*32;
        #pragma unroll
        for (int nj = 0; nj < 2; ++nj) {
            int colf = col_b + nj*32 + lr;
            float bv = bias[colf];
            int sel = (col_b + nj*32) >> 8;   // 0=Q,1=K,2=V (tile-uniform)
            int h = (colf >> 5) & 7;
            int d = colf & 31;
            #pragma unroll
            for (int r = 0; r < 16; ++r) {
                int r31 = (r & 3) + 8*(r >> 2) + 4*kg;
                int row = rb2 + r31;
                if (row >= M) continue;
                float v = acc[mi][nj][r] + bv;
                int bl = row / T_SEQ;
                int tok = row - bl * T_SEQ;
                size_t bb = (size_t)(bl*8 + h) * 12288;
                ushort hh = f2b_hi(v);
                ushort ll = f2b_lo(v, hh);
                if (sel == 0) {
                    size_t o = bb + (size_t)((tok >> 5)*4 + (d >> 3))*256
                             + ((tok & 31) << 3) + (d & 7);
                    Wq_h[o] = hh; Wq_l[o] = ll;
                } else if (sel == 1) {
                    size_t o = bb + (size_t)((tok >> 5)*4 + (d >> 3))*256
                             + ((tok & 31) << 3) + (d & 7);
                    Wk_h[o] = hh; Wk_l[o] = ll;
                } else {
                    size_t o = bb + (size_t)(tok >> 3)*256 + d*8 + (tok & 7);
                    Wv_h[o] = hh; Wv_l[o] = ll;
                }
            }
        }
    }
}

// ------- split-bf16 MFMA GEMM fused with residual add + LayerNorm -------
// (O-proj only now.) Block = 32 rows x 256 cols; in-place LN on x hi/lo.
__global__ __launch_bounds__(256) void gemm_ln(
    const ushort* __restrict__ Ahi, const ushort* __restrict__ Alo,
    const ushort* __restrict__ Bhi, const ushort* __restrict__ Blo,
    const float* __restrict__ bias,
    ushort* __restrict__ xhi, ushort* __restrict__ xlo,
    const float* __restrict__ g, const float* __restrict__ be,
    int M, int K)
{
    const int N = HDIM;
    const int t = threadIdx.x;
    const int lane = t & 63, wave = t >> 6;
    const int lr = lane & 31, kg = lane >> 5;
    const int row_b = blockIdx.y * 32;
    const int col_w = wave * 64;
    const int KB = K >> 3;

    const ushort *pAh, *pAl, *pBh[2], *pBl[2];
    {
        size_t base = ((size_t)(row_b >> 5) * KB + kg) * 256 + lr * 8;
        pAh = Ahi + base; pAl = Alo + base;
    }
    #pragma unroll
    for (int nj = 0; nj < 2; ++nj) {
        size_t base = ((size_t)((col_w + nj*32) >> 5) * KB + kg) * 256 + lr * 8;
        pBh[nj] = Bhi + base; pBl[nj] = Blo + base;
    }

    f32x16 acc[2];
    #pragma unroll
    for (int j = 0; j < 2; ++j)
        #pragma unroll
        for (int r = 0; r < 16; ++r) acc[j][r] = 0.f;

    bf16x8 a0h, a0l, b0h[2], b0l[2];
    bf16x8 a1h, a1l, b1h[2], b1l[2];

#define LOADF(AH, AL, BH, BL, OFF) do {                                        \
    AH = *reinterpret_cast<const bf16x8*>(pAh + (OFF));                        \
    AL = *reinterpret_cast<const bf16x8*>(pAl + (OFF));                        \
    _Pragma("unroll") for (int nj = 0; nj < 2; ++nj) {                         \
        BH[nj] = *reinterpret_cast<const bf16x8*>(pBh[nj] + (OFF));            \
        BL[nj] = *reinterpret_cast<const bf16x8*>(pBl[nj] + (OFF)); } } while(0)

#define MFMAF(AH, AL, BH, BL) do {                                             \
    _Pragma("unroll") for (int nj = 0; nj < 2; ++nj) {                         \
        acc[nj] = __builtin_amdgcn_mfma_f32_32x32x16_bf16(                     \
            AH, BH[nj], acc[nj], 0, 0, 0);                                     \
        acc[nj] = __builtin_amdgcn_mfma_f32_32x32x16_bf16(                     \
            AH, BL[nj], acc[nj], 0, 0, 0);                                     \
        acc[nj] = __builtin_amdgcn_mfma_f32_32x32x16_bf16(                     \
            AL, BH[nj], acc[nj], 0, 0, 0); } } while(0)

    LOADF(a0h, a0l, b0h, b0l, 0);
    for (int k0 = 0; k0 < K; k0 += 32) {
        size_t o1 = (size_t)((k0 + 16) >> 3) * 256;
        LOADF(a1h, a1l, b1h, b1l, o1);
        MFMAF(a0h, a0l, b0h, b0l);
        size_t o2 = (k0 + 32 < K) ? (size_t)((k0 + 32) >> 3) * 256 : 0;
        LOADF(a0h, a0l, b0h, b0l, o2);
        MFMAF(a1h, a1l, b1h, b1l);
    }
#undef LOADF
#undef MFMAF

    float s1[16], s2[16];
    #pragma unroll
    for (int nj = 0; nj < 2; ++nj) {
        int col = col_w + nj*32 + lr;
        float bv = bias[col];
        #pragma unroll
        for (int r = 0; r < 16; ++r) {
            int r31 = (r & 3) + 8*(r >> 2) + 4*kg;
            int row = row_b + r31;
            size_t oo = ((size_t)(row >> 5) * (N >> 3) + (col >> 3)) * 256
                      + ((row & 31) << 3) + (col & 7);
            float v = acc[nj][r] + bv + b2f(xhi[oo]) + b2f(xlo[oo]);
            acc[nj][r] = v;
            if (nj == 0) { s1[r] = v;  s2[r] = v*v; }
            else         { s1[r] += v; s2[r] += v*v; }
        }
    }
    #pragma unroll
    for (int r = 0; r < 16; ++r) {
        #pragma unroll
        for (int off = 1; off <= 16; off <<= 1) {
            s1[r] += __shfl_xor(s1[r], off);
            s2[r] += __shfl_xor(s2[r], off);
        }
    }
    __shared__ float red1[4][32];
    __shared__ float red2[4][32];
    __shared__ float tot1[32];
    __shared__ float tot2[32];
    if (lr == 0) {
        #pragma unroll
        for (int r = 0; r < 16; ++r) {
            int rr = (r & 3) + 8*(r >> 2) + 4*kg;
            red1[wave][rr] = s1[r];
            red2[wave][rr] = s2[r];
        }
    }
    __syncthreads();
    if (t < 32) {
        tot1[t] = red1[0][t] + red1[1][t] + red1[2][t] + red1[3][t];
        tot2[t] = red2[0][t] + red2[1][t] + red2[2][t] + red2[3][t];
    }
    __syncthreads();
    #pragma unroll
    for (int r = 0; r < 16; ++r) {
        int r31 = (r & 3) + 8*(r >> 2) + 4*kg;
        int row = row_b + r31;
        float mu = tot1[r31] * (1.f/256.f);
        float var = fmaf(-mu, mu, tot2[r31] * (1.f/256.f));
        float rs = rsqrtf(var + 1e-5f);
        #pragma unroll
        for (int nj = 0; nj < 2; ++nj) {
            int col = col_w + nj*32 + lr;
            float o = g[col] * (acc[nj][r] - mu) * rs + be[col];
            size_t oo = ((size_t)(row >> 5) * (N >> 3) + (col >> 3)) * 256
                      + ((row & 31) << 3) + (col & 7);
            ushort hh = f2b_hi(o);
            xhi[oo] = hh;
            xlo[oo] = f2b_lo(o, hh);
        }
    }
}

// ------- fused FF: x = LN(x + relu(x@Wf1+b1)@Wf2 + b2), hidden in registers -------
// One wave per 32-row strip. Stage 1 swapped (mfma(Wf1t, x) -> lane = x-row),
// per 32-wide n-tile: bias+relu, hi/lo exchange (attention's P table), stage 2
// accumulates 8 col-tiles. Wave-local LN epilogue. No LDS, no barriers.
__global__ __launch_bounds__(256) void ff_fused(
    const ushort* __restrict__ W1h, const ushort* __restrict__ W1l, // FT [1024][256]
    const ushort* __restrict__ W2h, const ushort* __restrict__ W2l, // FT [256][1024]
    const float* __restrict__ b1, const float* __restrict__ b2,
    ushort* __restrict__ xhi, ushort* __restrict__ xlo,
    const float* __restrict__ g, const float* __restrict__ be,
    int M)
{
    const int lane = threadIdx.x & 63, wave = threadIdx.x >> 6;
    const int lr = lane & 31, kg = lane >> 5;
    const int row_b = (blockIdx.x * 4 + wave) * 32;
    if (row_b >= M) return;

    const size_t xbase = ((size_t)(row_b >> 5) * 32) * 256 + lr * 8;

    f32x16 oacc[8];
    #pragma unroll
    for (int ct = 0; ct < 8; ++ct)
        #pragma unroll
        for (int r = 0; r < 16; ++r) oacc[ct][r] = 0.f;

    for (int nt = 0; nt < 32; ++nt) {
        // ---- stage 1: h^T tile (n = nt*32..+31, m = strip rows) ----
        f32x16 st;
        #pragma unroll
        for (int r = 0; r < 16; ++r) st[r] = 0.f;
        #pragma unroll
        for (int ks = 0; ks < 16; ++ks) {
            size_t wo = ((size_t)nt * 32 + ks * 2 + kg) * 256 + lr * 8;
            bf16x8 wh = *reinterpret_cast<const bf16x8*>(W1h + wo);
            bf16x8 wl = *reinterpret_cast<const bf16x8*>(W1l + wo);
            size_t xo = xbase + (size_t)(ks * 2 + kg) * 256;
            bf16x8 xh8 = *reinterpret_cast<const bf16x8*>(xhi + xo);
            bf16x8 xl8 = *reinterpret_cast<const bf16x8*>(xlo + xo);
            st = __builtin_amdgcn_mfma_f32_32x32x16_bf16(wh, xh8, st, 0,0,0);
            st = __builtin_amdgcn_mfma_f32_32x32x16_bf16(wh, xl8, st, 0,0,0);
            st = __builtin_amdgcn_mfma_f32_32x32x16_bf16(wl, xh8, st, 0,0,0);
        }
        // bias + relu: lane holds h[m=lr][n = nt*32 + r31]
        float p[16];
        #pragma unroll
        for (int r = 0; r < 16; ++r) {
            int n = nt*32 + (r & 3) + 8*(r >> 2) + 4*kg;
            p[r] = fmaxf(st[r] + b1[n], 0.f);
        }
        float pp[16];
        #pragma unroll
        for (int r = 0; r < 16; ++r) pp[r] = __shfl_xor(p[r], 32);
        // ---- exchange to A-frags + stage 2 ----
        #pragma unroll
        for (int ks = 0; ks < 2; ++ks) {
            union { u16x8 u; bf16x8 b; } fh, fl;
            #pragma unroll
            for (int j = 0; j < 8; ++j) {
                float e;
                if (ks == 0)
                    e = kg ? ((j < 4) ? pp[4+j] : p[j])
                           : ((j < 4) ? p[j]    : pp[j-4]);
                else
                    e = kg ? ((j < 4) ? pp[12+j] : p[8+j])
                           : ((j < 4) ? p[8+j]   : pp[4+j]);
                ushort hh = f2b_hi(e);
                fh.u[j] = hh;
                fl.u[j] = f2b_lo(e, hh);
            }
            #pragma unroll
            for (int ct = 0; ct < 8; ++ct) {
                size_t wo = ((size_t)ct * 128 + nt * 4 + ks * 2 + kg) * 256 + lr * 8;
                bf16x8 wh = *reinterpret_cast<const bf16x8*>(W2h + wo);
                bf16x8 wl = *reinterpret_cast<const bf16x8*>(W2l + wo);
                oacc[ct] = __builtin_amdgcn_mfma_f32_32x32x16_bf16(fh.b, wh, oacc[ct], 0,0,0);
                oacc[ct] = __builtin_amdgcn_mfma_f32_32x32x16_bf16(fh.b, wl, oacc[ct], 0,0,0);
                oacc[ct] = __builtin_amdgcn_mfma_f32_32x32x16_bf16(fl.b, wh, oacc[ct], 0,0,0);
            }
        }
    }
    // ---- epilogue: residual + wave-local LN ----
    // oacc[ct][r] = out(row = row_b + r31, col = ct*32 + lr)
    float s1[16], s2[16];
    #pragma unroll
    for (int ct = 0; ct < 8; ++ct) {
        int col = ct*32 + lr;
        float bv = b2[col];
        #pragma unroll
        for (int r = 0; r < 16; ++r) {
            int r31 = (r & 3) + 8*(r >> 2) + 4*kg;
            int row = row_b + r31;
            size_t oo = ((size_t)(row >> 5) * 32 + (col >> 3)) * 256
                      + ((row & 31) << 3) + (col & 7);
            float v = oacc[ct][r] + bv + b2f(xhi[oo]) + b2f(xlo[oo]);
            oacc[ct][r] = v;
            if (ct == 0) { s1[r] = v;  s2[r] = v*v; }
            else         { s1[r] += v; s2[r] += v*v; }
        }
    }
    #pragma unroll
    for (int r = 0; r < 16; ++r) {
        #pragma unroll
        for (int off = 1; off <= 16; off <<= 1) {
            s1[r] += __shfl_xor(s1[r], off);
            s2[r] += __shfl_xor(s2[r], off);
        }
    }
    #pragma unroll
    for (int r = 0; r < 16; ++r) {
        int r31 = (r & 3) + 8*(r >> 2) + 4*kg;
        int row = row_b + r31;
        float mu = s1[r] * (1.f/256.f);
        float var = fmaf(-mu, mu, s2[r] * (1.f/256.f));
        float rs = rsqrtf(var + 1e-5f);
        #pragma unroll
        for (int ct = 0; ct < 8; ++ct) {
            int col = ct*32 + lr;
            float o = g[col] * (oacc[ct][r] - mu) * rs + be[col];
            size_t oo = ((size_t)(row >> 5) * 32 + (col >> 3)) * 256
                      + ((row & 31) << 3) + (col & 7);
            ushort hh = f2b_hi(o);
            xhi[oo] = hh;
            xlo[oo] = f2b_lo(o, hh);
        }
    }
}

// ------- MFMA attention, one-pass online softmax: 1 wave per (b,h,q-tile) -------
// grid(CH*8, 3): bh on x so the 3 q-tile blocks of one bh share an XCD.
__global__ __launch_bounds__(256) void attn_mfma(
    const ushort* __restrict__ Qh, const ushort* __restrict__ Ql,
    const ushort* __restrict__ Kh, const ushort* __restrict__ Kl,
    const ushort* __restrict__ Vh, const ushort* __restrict__ Vl,
    ushort* __restrict__ ahi, ushort* __restrict__ alo)
{
    const int bh = blockIdx.x;
    const int wave = threadIdx.x >> 6, lane = threadIdx.x & 63;
    const int qt = blockIdx.y * 4 + wave;   // 0..11
    const int lr = lane & 31, kg = lane >> 5;
    const size_t base = (size_t)bh * 12288;
    const float scale = 0.17677669529663687f; // 1/sqrt(32)

    bf16x8 qfh[2], qfl[2];
    #pragma unroll
    for (int ks = 0; ks < 2; ++ks) {
        size_t o = base + (size_t)(qt*4 + ks*2 + kg)*256 + lr*8;
        qfh[ks] = *reinterpret_cast<const bf16x8*>(Qh + o);
        qfl[ks] = *reinterpret_cast<const bf16x8*>(Ql + o);
    }

    float m = -3e38f, l = 0.f;
    f32x16 oacc;
    #pragma unroll
    for (int r = 0; r < 16; ++r) oacc[r] = 0.f;

    for (int kt = 0; kt < 12; ++kt) {
        f32x16 st;
        #pragma unroll
        for (int r = 0; r < 16; ++r) st[r] = 0.f;
        #pragma unroll
        for (int ks = 0; ks < 2; ++ks) {
            size_t o = base + (size_t)(kt*4 + ks*2 + kg)*256 + lr*8;
            bf16x8 kfh = *reinterpret_cast<const bf16x8*>(Kh + o);
            bf16x8 kfl = *reinterpret_cast<const bf16x8*>(Kl + o);
            st = __builtin_amdgcn_mfma_f32_32x32x16_bf16(kfh, qfh[ks], st, 0,0,0);
            st = __builtin_amdgcn_mfma_f32_32x32x16_bf16(kfh, qfl[ks], st, 0,0,0);
            st = __builtin_amdgcn_mfma_f32_32x32x16_bf16(kfl, qfh[ks], st, 0,0,0);
        }
        float p[16];
        float tm = -3e38f;
        #pragma unroll
        for (int r = 0; r < 16; ++r) {
            int krow = kt*32 + (r & 3) + 8*(r >> 2) + 4*kg;
            p[r] = (krow < T_SEQ) ? st[r] : -3e38f;
            tm = fmaxf(tm, p[r]);
        }
        tm = fmaxf(tm, __shfl_xor(tm, 32));
        float newm = fmaxf(m, tm);
        float f = __expf((m - newm) * scale);
        m = newm;
        l *= f;
        float sumL = 0.f;
        #pragma unroll
        for (int r = 0; r < 16; ++r) {
            float e = __expf((p[r] - m) * scale);
            p[r] = e; sumL += e;
        }
        l += sumL;
        #pragma unroll
        for (int r = 0; r < 16; ++r) {
            int r31 = (r & 3) + 8*(r >> 2) + 4*kg;
            float fr = __shfl(f, r31);
            oacc[r] *= fr;
        }
        float pp[16];
        #pragma unroll
        for (int r = 0; r < 16; ++r) pp[r] = __shfl_xor(p[r], 32);
        #pragma unroll
        for (int ks = 0; ks < 2; ++ks) {
            union { u16x8 u; bf16x8 b; } fh, fl;
            #pragma unroll
            for (int j = 0; j < 8; ++j) {
                float e;
                if (ks == 0)
                    e = kg ? ((j < 4) ? pp[4+j] : p[j])
                           : ((j < 4) ? p[j]    : pp[j-4]);
                else
                    e = kg ? ((j < 4) ? pp[12+j] : p[8+j])
                           : ((j < 4) ? p[8+j]   : pp[4+j]);
                ushort hh = f2b_hi(e);
                fh.u[j] = hh;
                fl.u[j] = f2b_lo(e, hh);
            }
            size_t vo = base + (size_t)(kt*4 + ks*2 + kg)*256 + lr*8;
            bf16x8 vfh = *reinterpret_cast<const bf16x8*>(Vh + vo);
            bf16x8 vfl = *reinterpret_cast<const bf16x8*>(Vl + vo);
            oacc = __builtin_amdgcn_mfma_f32_32x32x16_bf16(fh.b, vfh, oacc, 0,0,0);
            oacc = __builtin_amdgcn_mfma_f32_32x32x16_bf16(fh.b, vfl, oacc, 0,0,0);
            oacc = __builtin_amdgcn_mfma_f32_32x32x16_bf16(fl.b, vfh, oacc, 0,0,0);
        }
    }
    l += __shfl_xor(l, 32);
    float il = 1.f / l;

    const int bl = bh >> 3, h = bh & 7;
    #pragma unroll
    for (int r = 0; r < 16; ++r) {
        int q = (r & 3) + 8*(r >> 2) + 4*kg;
        float sc = __shfl(il, q);
        int row_local = qt*32 + q;
        if (row_local < T_SEQ) {
            float v = oacc[r] * sc;
            int grow = bl*T_SEQ + row_local;
            int col = h*32 + lr;
            size_t o = ((size_t)(grow >> 5)*32 + (col >> 3))*256
                     + ((grow & 31) << 3) + (col & 7);
            ushort hh = f2b_hi(v);
            ahi[o] = hh;
            alo[o] = f2b_lo(v, hh);
        }
    }
}

// -------- per-chunk mean-pool over t (chunk-local x -> global pooled) --------
__global__ __launch_bounds__(256) void pool_kernel(
    const ushort* __restrict__ xhi, const ushort* __restrict__ xlo,
    float* __restrict__ pooled)
{
    int b = blockIdx.x, t = threadIdx.x;
    float acc = 0.f;
    for (int tt = 0; tt < T_SEQ; ++tt) {
        size_t row = (size_t)b*T_SEQ + tt;
        size_t o = ((row >> 5) * 32 + (t >> 3)) * 256 + ((row & 31) << 3) + (t & 7);
        acc += b2f(xhi[o]) + b2f(xlo[o]);
    }
    pooled[(size_t)b*HDIM + t] = acc * (1.f/365.f);
}

// -------- output head (reads pooled + sfeat) --------
__global__ __launch_bounds__(256) void head_kernel(
    const float* __restrict__ pooled, const float* __restrict__ sfeat,
    const float* __restrict__ W1, const float* __restrict__ b1,
    const float* __restrict__ W2, const float* __restrict__ b2,
    const float* __restrict__ scale, const float* __restrict__ shift,
    float* __restrict__ out)
{
    __shared__ float p[HDIM];
    __shared__ float h1[HDIM/2];
    int b = blockIdx.x, t = threadIdx.x;
    p[t] = pooled[(size_t)b*HDIM + t] + sfeat[(size_t)b*HDIM + t];
    __syncthreads();
    if (t < HDIM/2) {
        float a = b1[t];
        for (int c = 0; c < HDIM; ++c) a = fmaf(p[c], W1[c*(HDIM/2) + t], a);
        h1[t] = gelu_f(a);
    }
    __syncthreads();
    if (t < 30) {
        float a = b2[t];
        for (int j = 0; j < HDIM/2; ++j) a = fmaf(h1[j], W2[j*30 + t], a);
        out[b*30 + t] = tanhf(a) * scale[0] + shift[0];
    }
}

extern "C" void kernel_launch(void* const* d_in, const int* in_sizes, int n_in,
                              void* d_out, int out_size, void* d_ws, size_t ws_size,
                              hipStream_t stream) {
    const float* p_static = (const float*)d_in[0];
    const float* p_dyn    = (const float*)d_in[1];
    const float* p_lat    = (const float*)d_in[2];
    const float* p_lon    = (const float*)d_in[3];
    const float* p_all    = (const float*)d_in[4];
    const float* p_coords = (const float*)d_in[5];
    const float* p_Wst    = (const float*)d_in[6];
    const float* p_bst    = (const float*)d_in[7];
    const float* p_gst    = (const float*)d_in[8];
    const float* p_best   = (const float*)d_in[9];
    const float* p_Wdy    = (const float*)d_in[10];
    const float* p_bdy    = (const float*)d_in[11];
    const float* p_gdy    = (const float*)d_in[12];
    const float* p_bedy   = (const float*)d_in[13];
    const float* p_Wqkv   = (const float*)d_in[14];
    const float* p_bqkv   = (const float*)d_in[15];
    const float* p_Wo     = (const float*)d_in[16];
    const float* p_bo     = (const float*)d_in[17];
    const float* p_gln1   = (const float*)d_in[18];
    const float* p_beln1  = (const float*)d_in[19];
    const float* p_Wf1    = (const float*)d_in[20];
    const float* p_bf1    = (const float*)d_in[21];
    const float* p_Wf2    = (const float*)d_in[22];
    const float* p_bf2    = (const float*)d_in[23];
    const float* p_gln2   = (const float*)d_in[24];
    const float* p_beln2  = (const float*)d_in[25];
    const float* p_Wo1    = (const float*)d_in[26];
    const float* p_bo1    = (const float*)d_in[27];
    const float* p_Wo2    = (const float*)d_in[28];
    const float* p_bo2    = (const float*)d_in[29];
    const float* p_scale  = (const float*)d_in[30];
    const float* p_shift  = (const float*)d_in[31];
    float* out = (float*)d_out;
    (void)in_sizes; (void)n_in; (void)out_size;

    char* ws = (char*)d_ws;
    size_t off = 0;
    auto alloc = [&](size_t bytes) -> void* {
        void* p = ws + off;
        off += (bytes + 255) & ~(size_t)255;
        return p;
    };
    int*    nbr    = (int*)   alloc((size_t)BATCH*KNB*sizeof(int));
    float*  sfeat  = (float*) alloc((size_t)BATCH*HDIM*sizeof(float));
    float*  pooled = (float*) alloc((size_t)BATCH*HDIM*sizeof(float));
    const size_t SZ_QKV = (size_t)4*768*256, SZ_O = (size_t)4*256*256;
    const size_t SZ_F1  = (size_t)4*1024*256, SZ_F2 = (size_t)4*256*1024;
    ushort* Wqkvt_h = (ushort*)alloc(SZ_QKV*2*sizeof(ushort)); ushort* Wqkvt_l = Wqkvt_h + SZ_QKV;
    ushort* Wot_h   = (ushort*)alloc(SZ_O  *2*sizeof(ushort)); ushort* Wot_l   = Wot_h   + SZ_O;
    ushort* Wf1t_h  = (ushort*)alloc(SZ_F1 *2*sizeof(ushort)); ushort* Wf1t_l  = Wf1t_h  + SZ_F1;
    ushort* Wf2t_h  = (ushort*)alloc(SZ_F2 *2*sizeof(ushort)); ushort* Wf2t_l  = Wf2t_h  + SZ_F2;
    size_t fixed = off;

    // per-chunk: x hi/lo (373,760 B/batch) + union region (attn QKV-split +
    // aatt = 1,553,408 B/batch; FF now buffer-free).
    const size_t X_CH   = (size_t)T_SEQ * HDIM * 4;     // 373,760
    const size_t REG_CH = (size_t)1553408;
    const size_t PER_CH = X_CH + REG_CH;                // 1,927,168
    int CH = 32;
    {
        const int tiers[3] = {256, 128, 64};
        for (int i = 0; i < 3; ++i) {
            if (fixed + (size_t)tiers[i]*PER_CH + 8192 <= ws_size) { CH = tiers[i]; break; }
        }
    }
    const int RW = CH * T_SEQ;
    ushort* xh  = (ushort*)alloc((size_t)CH * X_CH);
    ushort* xl  = xh + (size_t)RW * HDIM;
    char*   big = (char*)alloc((size_t)CH * REG_CH);
    const size_t seg = (size_t)CH * 8 * 12288;          // ushorts per QKV buffer
    ushort* Qh  = (ushort*)big;
    ushort* Ql  = Qh  + seg;
    ushort* Kh2 = Ql  + seg;
    ushort* Kl2 = Kh2 + seg;
    ushort* Vth = Kl2 + seg;
    ushort* Vtl = Vth + seg;
    ushort* aatt_h = Vtl + seg;
    ushort* aatt_l = aatt_h + (size_t)RW * HDIM;
    const int GY  = (RW + 127) / 128;   // 128-row tiles (guarded)
    const int GY3 = RW / 32;            // 32-row tiles (exact: RW%32==0)
    const int GFF = (RW/32 + 3) / 4;    // ff_fused blocks (4 strips each, guarded)

    topk_kernel <<<BATCH, 256, 0, stream>>>(p_lat, p_lon, p_coords, nbr);
    sfeat_kernel<<<BATCH, 256, 0, stream>>>(p_static, p_all, nbr, p_Wst, p_bst, p_gst, p_best, sfeat);
    tsplit_kernel<<<dim3(24, 8, 4), 256, 0, stream>>>(p_Wqkv, Wqkvt_h, Wqkvt_l, 256, 768);
    tsplit_kernel<<<dim3( 8, 8, 4), 256, 0, stream>>>(p_Wo,   Wot_h,   Wot_l,   256, 256);
    tsplit_kernel<<<dim3(32, 8, 4), 256, 0, stream>>>(p_Wf1,  Wf1t_h,  Wf1t_l,  256, 1024);
    tsplit_kernel<<<dim3( 8,32, 4), 256, 0, stream>>>(p_Wf2,  Wf2t_h,  Wf2t_l,  1024, 256);

    const int NCHUNK = BATCH / CH;
    for (int c = 0; c < NCHUNK; ++c) {
        dyn_kernel<<<RW/4, 256, 0, stream>>>(
            p_dyn + (size_t)c*CH*T_SEQ*DDIM, p_Wdy, p_bdy, p_gdy, p_bedy,
            sfeat + (size_t)c*CH*HDIM, xh, xl);
        for (int l = 0; l < 4; ++l) {
            gemm_qkv<<<dim3(6, GY), 256, 0, stream>>>(
                xh, xl, Wqkvt_h + (size_t)l*768*256, Wqkvt_l + (size_t)l*768*256,
                p_bqkv + l*768,
                Qh, Ql, Kh2, Kl2, Vth, Vtl, RW, 768, 256);
            attn_mfma<<<dim3(CH*8, 3), 256, 0, stream>>>(
                Qh, Ql, Kh2, Kl2, Vth, Vtl, aatt_h, aatt_l);
            gemm_ln<<<dim3(1, GY3), 256, 0, stream>>>(
                aatt_h, aatt_l, Wot_h + (size_t)l*256*256, Wot_l + (size_t)l*256*256,
                p_bo + l*256, xh, xl, p_gln1 + l*256, p_beln1 + l*256, RW, 256);
            ff_fused<<<GFF, 256, 0, stream>>>(
                Wf1t_h + (size_t)l*1024*256, Wf1t_l + (size_t)l*1024*256,
                Wf2t_h + (size_t)l*256*1024, Wf2t_l + (size_t)l*256*1024,
                p_bf1 + l*1024, p_bf2 + l*256,
                xh, xl, p_gln2 + l*256, p_beln2 + l*256, RW);
        }
        pool_kernel<<<CH, 256, 0, stream>>>(xh, xl, pooled + (size_t)c*CH*HDIM);
    }
    head_kernel<<<BATCH, 256, 0, stream>>>(pooled, sfeat, p_Wo1, p_bo1, p_Wo2, p_bo2, p_scale, p_shift, out);
}